// Round 8
// baseline (328.961 us; speedup 1.0000x reference)
//
#include <hip/hip_runtime.h>
#include <math.h>

// Problem constants (fixed by setup_inputs)
#define BB 72      // G * SAMPLE_NUMS = 8*9
#define SS 512
#define HH 768
#define GG 8
#define SN 9
#define VR 2       // VIEW_RANGE
#define NT 16      // distinct turn values (randint(0,16))
#define NPART 32   // cross-num partials per batch (one per k_ct block)

// Output is FP32, layout = return order [loss | q | a | n] (verified).
// Inputs fp32, dict order.
//
// Bucket factorization (verified round 2): band(t) depends only on v=turn_t:
//   G_i^(u)[h] = sum_{turn_s=u, id_s=i} am_s^2 x_s[h]      (k_g, one x pass)
//   W_i^(v)    = sum_{u in [v-2,v+2]} G_i^(u)              (k_w, G read once)
//   d_i(t)     = x_t . W_i^(turn_t)                        (k_ct, one x pass)
// Round 18: raise wave-level parallelism everywhere. k_g -> 6 waves/block
// (2-group run split + LDS combine, 6912 waves). k_ct -> 2304 blocks, 4 t's
// per wave (9216 waves), 2-deep x prefetch. k_w also emits snum (G column
// sums) so k_cos loses its strided G latency chain.

__device__ float g_G [(size_t)BB * NT * 4 * HH];       // 14.2 MB
__device__ float g_Wm[(size_t)BB * NT * 4 * HH];       // 14.2 MB (windowed)
__device__ float g_snum[BB * 3 * HH];                  // self numerators
__device__ float g_xpart[(size_t)BB * NPART * 3 * HH]; // cross-num block partials
__device__ float g_logits[3 * BB];

__device__ __forceinline__ void class_masks(float am, int id, float& qv, float& av, float& nv) {
    qv = (id == 1 || id == 2) ? am : 0.0f;
    av = (id == 0 || id == 2) ? am : 0.0f;
    nv = (id == 3) ? am : 0.0f;
}

// ---------------------------------------------------------------------------
// k_g: grid (NT, BB), block 384 = 6 waves in two 192-thread groups.
// Block (u,b): binary-search run [beg,end) over LDS tn; group g sums rows
// beg+g, beg+g+2, ... (wave-uniform) id-split into 4 float4 register
// accumulators; groups combined through a 12 KB LDS stage; G[b][u] written
// once (empty run -> zeros). 8-deep guarded row batches per group.
// ---------------------------------------------------------------------------
__global__ __launch_bounds__(384) void k_g(const float* __restrict__ x,
                                           const float* __restrict__ am,
                                           const int* __restrict__ qa,
                                           const int* __restrict__ turn) {
    __shared__ int   tn[SS];
    __shared__ float c2s[SS];
    __shared__ int   idvs[SS];
    __shared__ float Gh[4 * HH];   // 12 KB combine buffer

    const int u = blockIdx.x, b = blockIdx.y;
    const int tid = threadIdx.x;
    const int grp = (tid >= 192) ? 1 : 0;
    const int lt  = tid - grp * 192;          // lt*4 = h base (192*4 = 768)

    for (int i = tid; i < SS; i += 384) tn[i] = turn[b * SS + i];
    __syncthreads();

    // run bounds: [beg, end) with tn == u  (tn sorted ascending)
    int L = 0, R = SS;
    while (L < R) { int m = (L + R) >> 1; if (tn[m] < u) L = m + 1; else R = m; }
    const int beg = L;
    L = beg; R = SS;
    while (L < R) { int m = (L + R) >> 1; if (tn[m] <= u) L = m + 1; else R = m; }
    const int end = L;

    for (int i = beg + tid; i < end; i += 384) {
        float a = am[b * SS + i]; c2s[i] = a * a;
        idvs[i] = qa[b * SS + i];
    }
    __syncthreads();

    float4 acc[4];
#pragma unroll
    for (int i = 0; i < 4; ++i) acc[i] = make_float4(0.f, 0.f, 0.f, 0.f);

    const float* xb = x + (size_t)b * SS * HH + lt * 4;
    for (int s0 = beg; s0 < end; s0 += 16) {
        float4 v[8];
#pragma unroll
        for (int k = 0; k < 8; ++k) {
            const int ss = s0 + 2 * k + grp;
            v[k] = (ss < end) ? *(const float4*)(xb + (size_t)ss * HH)
                              : make_float4(0.f, 0.f, 0.f, 0.f);
        }
#pragma unroll
        for (int k = 0; k < 8; ++k) {
            const int ss = s0 + 2 * k + grp;
            if (ss < end) {                       // wave-uniform (group-wide)
                const float cc = c2s[ss];
                const int id = idvs[ss];
                const float4 xv = v[k];
                if (id == 0) { acc[0].x += xv.x * cc; acc[0].y += xv.y * cc;
                               acc[0].z += xv.z * cc; acc[0].w += xv.w * cc; }
                else if (id == 1) { acc[1].x += xv.x * cc; acc[1].y += xv.y * cc;
                                    acc[1].z += xv.z * cc; acc[1].w += xv.w * cc; }
                else if (id == 2) { acc[2].x += xv.x * cc; acc[2].y += xv.y * cc;
                                    acc[2].z += xv.z * cc; acc[2].w += xv.w * cc; }
                else { acc[3].x += xv.x * cc; acc[3].y += xv.y * cc;
                       acc[3].z += xv.z * cc; acc[3].w += xv.w * cc; }
            }
        }
    }

    if (grp == 1) {
#pragma unroll
        for (int i = 0; i < 4; ++i)
            *(float4*)&Gh[i * HH + lt * 4] = acc[i];
    }
    __syncthreads();
    if (grp == 0) {
        float* go = g_G + ((size_t)(b * NT + u) * 4) * HH + lt * 4;
#pragma unroll
        for (int i = 0; i < 4; ++i) {
            const float4 o = *(const float4*)&Gh[i * HH + lt * 4];
            float4 s;
            s.x = acc[i].x + o.x; s.y = acc[i].y + o.y;
            s.z = acc[i].z + o.z; s.w = acc[i].w + o.w;
            *(float4*)(go + (size_t)i * HH) = s;
        }
    }
}

// ---------------------------------------------------------------------------
// k_w: W[b][v] = sum_{u in [v-2,v+2]} G[b][u]; also emits snum (column sums
// of G: sq = T1+T2, sa = T0+T2, sn = T3). grid (4, BB): block owns a
// 192-float h-quarter; stages G[b][*][*][quarter] (48 KB) in LDS once.
// ---------------------------------------------------------------------------
__global__ __launch_bounds__(256) void k_w() {
    __shared__ float Gl[NT * 4 * 192];   // 48 KB
    const int qh = blockIdx.x, b = blockIdx.y, tid = threadIdx.x;

    for (int idx = tid * 4; idx < NT * 4 * 192; idx += 1024) {
        const int u = idx / 768, rem = idx % 768;
        const int i = rem / 192, hh = rem % 192;
        *(float4*)&Gl[idx] =
            *(const float4*)(g_G + ((size_t)(b * NT + u) * 4 + i) * HH + qh * 192 + hh);
    }
    __syncthreads();

    for (int idx = tid * 4; idx < NT * 4 * 192; idx += 1024) {
        const int v = idx / 768, rem = idx % 768;
        const int i = rem / 192, hh = rem % 192;
        const int ulo = (v - VR < 0) ? 0 : v - VR;
        const int uhi = (v + VR > NT - 1) ? NT - 1 : v + VR;
        float4 s = make_float4(0.f, 0.f, 0.f, 0.f);
        for (int u = ulo; u <= uhi; ++u) {
            const float4 gv = *(const float4*)&Gl[(u * 4 + i) * 192 + hh];
            s.x += gv.x; s.y += gv.y; s.z += gv.z; s.w += gv.w;
        }
        *(float4*)(g_Wm + ((size_t)(b * NT + v) * 4 + i) * HH + qh * 192 + hh) = s;
    }

    // snum for this h-quarter (threads 0..47 own a float4 each)
    if (tid < 48) {
        const int hh = tid * 4;
        float4 t0 = make_float4(0.f,0.f,0.f,0.f), t1 = t0, t2 = t0, t3 = t0;
        for (int u = 0; u < NT; ++u) {
            const float4 g0 = *(const float4*)&Gl[(u * 4 + 0) * 192 + hh];
            const float4 g1 = *(const float4*)&Gl[(u * 4 + 1) * 192 + hh];
            const float4 g2 = *(const float4*)&Gl[(u * 4 + 2) * 192 + hh];
            const float4 g3 = *(const float4*)&Gl[(u * 4 + 3) * 192 + hh];
            t0.x += g0.x; t0.y += g0.y; t0.z += g0.z; t0.w += g0.w;
            t1.x += g1.x; t1.y += g1.y; t1.z += g1.z; t1.w += g1.w;
            t2.x += g2.x; t2.y += g2.y; t2.z += g2.z; t2.w += g2.w;
            t3.x += g3.x; t3.y += g3.y; t3.z += g3.z; t3.w += g3.w;
        }
        float4 oq, oa, on;
        oq.x = t1.x + t2.x; oq.y = t1.y + t2.y; oq.z = t1.z + t2.z; oq.w = t1.w + t2.w;
        oa.x = t0.x + t2.x; oa.y = t0.y + t2.y; oa.z = t0.z + t2.z; oa.w = t0.w + t2.w;
        on = t3;
        *(float4*)(g_snum + (size_t)(b * 3 + 0) * HH + qh * 192 + hh) = oq;
        *(float4*)(g_snum + (size_t)(b * 3 + 1) * HH + qh * 192 + hh) = oa;
        *(float4*)(g_snum + (size_t)(b * 3 + 2) * HH + qh * 192 + hh) = on;
    }
}

// ---------------------------------------------------------------------------
// k_ct: per t: d_i = x_t . W_i^(turn_t), W from g_Wm per v-change. Wave owns
// 4 t's (grid (SS/16=32, BB) = 2304 blocks, 9216 waves); 2-deep rolling x-row
// prefetch. Epilogue algebra -> cw_{q,a,n}(t); cross numerators accumulated
// in registers; block reduce via 9 KB LDS ds_add (NPART=32).
// lane owns h = ch*256 + lane*4 + {0..3}, ch = 0..2.
// ---------------------------------------------------------------------------
__global__ __launch_bounds__(256) void k_ct(const float* __restrict__ x,
                                            const float* __restrict__ am,
                                            const int* __restrict__ qa,
                                            const int* __restrict__ turn) {
    __shared__ float red[3 * HH];      // 9 KB
    __shared__ int   tnb[16];
    __shared__ float amb[16];
    __shared__ int   idb[16];

    const int b = blockIdx.y, ts = blockIdx.x, T0 = ts * 16;
    const int tid = threadIdx.x, w = tid >> 6, lane = tid & 63;
    if (tid < 16) {
        tnb[tid] = turn[b * SS + T0 + tid];
        amb[tid] = am[b * SS + T0 + tid];
        idb[tid] = qa[b * SS + T0 + tid];
    }
    for (int idx = tid; idx < 3 * HH; idx += 256) red[idx] = 0.0f;
    __syncthreads();

    const float* xb = x + (size_t)b * SS * HH + lane * 4;

    float xn[3][12];
#pragma unroll
    for (int c = 0; c < 3; ++c)
#pragma unroll
        for (int k = 0; k < 12; ++k) xn[c][k] = 0.0f;

    float4 Wr[4][3];
    int curv = -1;

    // 2-deep rolling prefetch of the wave's 4 x-rows
    const float* xr0 = xb + (size_t)(T0 + w * 4) * HH;
    float4 xA[3], xB[3];
    xA[0] = *(const float4*)(xr0 + 0);
    xA[1] = *(const float4*)(xr0 + 256);
    xA[2] = *(const float4*)(xr0 + 512);

#pragma unroll
    for (int it = 0; it < 4; ++it) {
        if (it < 3) {
            const float* xr = xb + (size_t)(T0 + w * 4 + it + 1) * HH;
            xB[0] = *(const float4*)(xr + 0);
            xB[1] = *(const float4*)(xr + 256);
            xB[2] = *(const float4*)(xr + 512);
        }
        const int tl = w * 4 + it;
        const int v = tnb[tl];                 // wave-uniform
        if (v != curv) {
            curv = v;
            const float* Wg = g_Wm + ((size_t)(b * NT + v) * 4) * HH + lane * 4;
#pragma unroll
            for (int i = 0; i < 4; ++i) {
                Wr[i][0] = *(const float4*)(Wg + (size_t)i * HH + 0);
                Wr[i][1] = *(const float4*)(Wg + (size_t)i * HH + 256);
                Wr[i][2] = *(const float4*)(Wg + (size_t)i * HH + 512);
            }
        }
        float d[4];
#pragma unroll
        for (int i = 0; i < 4; ++i) {
            float s = 0;
#pragma unroll
            for (int ch = 0; ch < 3; ++ch) {
                s += xA[ch].x * Wr[i][ch].x + xA[ch].y * Wr[i][ch].y
                   + xA[ch].z * Wr[i][ch].z + xA[ch].w * Wr[i][ch].w;
            }
            d[i] = s;
        }
#pragma unroll
        for (int off = 32; off; off >>= 1) {
#pragma unroll
            for (int i = 0; i < 4; ++i) d[i] += __shfl_xor(d[i], off);
        }
        float qt, at, nt; class_masks(amb[tl], idb[tl], qt, at, nt);
        const float ant = at + nt, qnt = qt + nt, qat = qt + at;
        const float Sqq = d[1] + d[2], Sqa = d[2], Saa = d[0] + d[2], Snn = d[3];
        const float cwq = qt * (ant * Sqa + qnt * Saa + qat * Snn);
        const float cwa = at * (ant * Sqq + qnt * Sqa + qat * Snn);
        const float cwn = nt * (ant * (Sqq + Sqa) + qnt * (Sqa + Saa));
#pragma unroll
        for (int ch = 0; ch < 3; ++ch) {
            const float4 xv = xA[ch];
            xn[0][ch * 4 + 0] += cwq * xv.x; xn[0][ch * 4 + 1] += cwq * xv.y;
            xn[0][ch * 4 + 2] += cwq * xv.z; xn[0][ch * 4 + 3] += cwq * xv.w;
            xn[1][ch * 4 + 0] += cwa * xv.x; xn[1][ch * 4 + 1] += cwa * xv.y;
            xn[1][ch * 4 + 2] += cwa * xv.z; xn[1][ch * 4 + 3] += cwa * xv.w;
            xn[2][ch * 4 + 0] += cwn * xv.x; xn[2][ch * 4 + 1] += cwn * xv.y;
            xn[2][ch * 4 + 2] += cwn * xv.z; xn[2][ch * 4 + 3] += cwn * xv.w;
        }
#pragma unroll
        for (int ch = 0; ch < 3; ++ch) xA[ch] = xB[ch];
    }

    // block reduce: 4 waves ds_add into one buffer
#pragma unroll
    for (int c = 0; c < 3; ++c)
#pragma unroll
        for (int ch = 0; ch < 3; ++ch)
#pragma unroll
            for (int k = 0; k < 4; ++k)
                atomicAdd(&red[c * HH + ch * 256 + lane * 4 + k], xn[c][ch * 4 + k]);
    __syncthreads();

    float* xo = g_xpart + (size_t)(b * NPART + ts) * 3 * HH;
    for (int idx = tid * 4; idx < 3 * HH; idx += 1024)
        *(float4*)(xo + idx) = *(float4*)&red[idx];
}

// ---------------------------------------------------------------------------
// k_cos: dens + cosine logits per class c; snum read directly (from k_w);
// fp32 self-avg outputs for group sample 0 at out[1 + (c*GG + g)*HH + h].
// grid (3, BB), block 256.
// ---------------------------------------------------------------------------
__global__ void k_cos(const float* __restrict__ am, const int* __restrict__ qa,
                      float* __restrict__ out) {
    const int c = blockIdx.x, b = blockIdx.y, tid = threadIdx.x;
    const int wave = tid >> 6, lane = tid & 63;
    __shared__ float redd[4][3];
    __shared__ float sD[3];

    float q = 0, a = 0, n = 0;
    for (int s = tid; s < SS; s += 256) {
        float m = am[b * SS + s]; int id = qa[b * SS + s];
        float qv, av, nv; class_masks(m, id, qv, av, nv);
        q += qv; a += av; n += nv;
    }
#pragma unroll
    for (int off = 32; off; off >>= 1) {
        q += __shfl_down(q, off); a += __shfl_down(a, off); n += __shfl_down(n, off);
    }
    if (lane == 0) { redd[wave][0] = q; redd[wave][1] = a; redd[wave][2] = n; }
    __syncthreads();
    if (tid == 0) {
        float Q = 0, A = 0, N = 0;
#pragma unroll
        for (int w = 0; w < 4; ++w) { Q += redd[w][0]; A += redd[w][1]; N += redd[w][2]; }
        sD[0] = Q; sD[1] = A; sD[2] = N;
    }
    __syncthreads();
    const float Dq = sD[0], Da = sD[1], Dn = sD[2];
    const float Dself = (c == 0) ? Dq : ((c == 1) ? Da : Dn);
    const float Dcross = (c == 0) ? (Da + Dn) : ((c == 1) ? (Dq + Dn) : (Dq + Da));
    const float invS = 1.0f / (Dself + 1e-6f), invC = 1.0f / (Dcross + 1e-6f);

    float dot = 0, n1 = 0, n2 = 0;
#pragma unroll
    for (int j = 0; j < 3; ++j) {
        const int h = tid + j * 256;
        float sv = g_snum[(size_t)(b * 3 + c) * HH + h];
        float cv = 0;
        const float* xp = g_xpart + ((size_t)b * NPART * 3 + c) * HH + h;
#pragma unroll 8
        for (int p = 0; p < NPART; ++p) cv += xp[(size_t)p * 3 * HH];
        sv *= invS; cv *= invC;
        dot += sv * cv; n1 += sv * sv; n2 += cv * cv;
        if (b % SN == 0)
            out[1 + ((size_t)c * GG + b / SN) * HH + h] = sv;
    }
#pragma unroll
    for (int off = 32; off; off >>= 1) {
        dot += __shfl_down(dot, off); n1 += __shfl_down(n1, off); n2 += __shfl_down(n2, off);
    }
    __shared__ float red2[4][3];
    if (lane == 0) { red2[wave][0] = dot; red2[wave][1] = n1; red2[wave][2] = n2; }
    __syncthreads();
    if (tid == 0) {
        float D = 0, N1 = 0, N2 = 0;
#pragma unroll
        for (int w = 0; w < 4; ++w) { D += red2[w][0]; N1 += red2[w][1]; N2 += red2[w][2]; }
        float nx = fmaxf(sqrtf(N1), 1e-8f);
        float ny = fmaxf(sqrtf(N2), 1e-8f);
        float cc = D / (nx * ny);
        if (cc == 1.0f) cc = __uint_as_float(0x7FC00000u);
        g_logits[c * BB + b] = cc / 0.07f;
    }
}

// log_softmax + nanmean loss across 3 classes -> out[0] (fp32). (unchanged)
__global__ void k_loss(const float* __restrict__ labels, float* __restrict__ out) {
    __shared__ float rs[24];
    __shared__ int rc[24];
    const int tid = threadIdx.x;
    if (tid < 24) {
        int c = tid / GG, g = tid % GG;
        float lg[SN]; bool anynan = false;
        for (int j = 0; j < SN; ++j) {
            float v = g_logits[c * BB + g * SN + j];
            lg[j] = v;
            anynan = anynan || isnan(v);
        }
        float ssum = 0; int cnt = 0;
        if (!anynan) {
            float m = -1e30f;
            for (int j = 0; j < SN; ++j) m = fmaxf(m, lg[j]);
            float se = 0;
            for (int j = 0; j < SN; ++j) se += expf(lg[j] - m);
            float lse = m + logf(se);
            for (int j = 0; j < SN; ++j) ssum += (lg[j] - lse) * labels[g * SN + j];
            cnt = SN;
        }
        rs[tid] = ssum; rc[tid] = cnt;
    }
    __syncthreads();
    if (tid == 0) {
        float total = 0;
        for (int c = 0; c < 3; ++c) {
            float s = 0; int n = 0;
            for (int g = 0; g < GG; ++g) { s += rs[c * GG + g]; n += rc[c * GG + g]; }
            total += -(s / (float)n);
        }
        out[0] = total / 3.0f;
    }
}

extern "C" void kernel_launch(void* const* d_in, const int* in_sizes, int n_in,
                              void* d_out, int out_size, void* d_ws, size_t ws_size,
                              hipStream_t stream) {
    const float* x      = (const float*)d_in[0];
    const float* am     = (const float*)d_in[1];
    const float* labels = (const float*)d_in[2];
    const int*   qa     = (const int*)d_in[3];
    const int*   turn   = (const int*)d_in[4];
    float* out = (float*)d_out;

    k_g   <<<dim3(NT, BB),      384, 0, stream>>>(x, am, qa, turn);
    k_w   <<<dim3(4, BB),       256, 0, stream>>>();
    k_ct  <<<dim3(SS / 16, BB), 256, 0, stream>>>(x, am, qa, turn);
    k_cos <<<dim3(3, BB),       256, 0, stream>>>(am, qa, out);
    k_loss<<<dim3(1),           64,  0, stream>>>(labels, out);
}

// Round 9
// 242.932 us; speedup vs baseline: 1.3541x; 1.3541x over previous
//
#include <hip/hip_runtime.h>
#include <math.h>

// Problem constants (fixed by setup_inputs)
#define BB 72      // G * SAMPLE_NUMS = 8*9
#define SS 512
#define HH 768
#define GG 8
#define SN 9
#define VR 2       // VIEW_RANGE
#define NT 16      // distinct turn values (randint(0,16))
#define NPART 16   // cross-num partials per batch (one per k_ct block)

// Output is FP32, layout = return order [loss | q | a | n] (verified).
// Inputs fp32, dict order.
//
// Bucket factorization (verified round 2): band(t) depends only on v=turn_t:
//   G_i^(u)[h] = sum_{turn_s=u, id_s=i} am_s^2 x_s[h]      (k_g, one x pass)
//   W_i^(v)    = sum_{u in [v-2,v+2]} G_i^(u)              (k_w, G read once)
//   d_i(t)     = x_t . W_i^(turn_t)                        (k_ct, one x pass)
// Round 19: k_ct reverted to the round-4 measured-best shape (8 t/wave,
// 37 KB tree reduce, NPART=16) with two strict upgrades: direct g_Wm loads
// (12 vs 60 per v-change) and first-W prefetch hoisted beside the x prefetch
// (~36 loads in flight before any compute). Round-8 lesson: thin waves
// double fixed costs; parallelism was not the constraint.

__device__ float g_G [(size_t)BB * NT * 4 * HH];       // 14.2 MB
__device__ float g_Wm[(size_t)BB * NT * 4 * HH];       // 14.2 MB (windowed)
__device__ float g_snum[BB * 3 * HH];                  // self numerators
__device__ float g_xpart[(size_t)BB * NPART * 3 * HH]; // cross-num block partials
__device__ float g_logits[3 * BB];

__device__ __forceinline__ void class_masks(float am, int id, float& qv, float& av, float& nv) {
    qv = (id == 1 || id == 2) ? am : 0.0f;
    av = (id == 0 || id == 2) ? am : 0.0f;
    nv = (id == 3) ? am : 0.0f;
}

// ---------------------------------------------------------------------------
// k_g: grid (NT, BB), block 384 = 6 waves in two 192-thread groups.
// Block (u,b): binary-search run [beg,end) over LDS tn; group g sums rows
// beg+g, beg+g+2, ... (wave-uniform) id-split into 4 float4 register
// accumulators; groups combined through a 12 KB LDS stage; G[b][u] written
// once (empty run -> zeros). 8-deep guarded row batches per group.
// ---------------------------------------------------------------------------
__global__ __launch_bounds__(384) void k_g(const float* __restrict__ x,
                                           const float* __restrict__ am,
                                           const int* __restrict__ qa,
                                           const int* __restrict__ turn) {
    __shared__ int   tn[SS];
    __shared__ float c2s[SS];
    __shared__ int   idvs[SS];
    __shared__ float Gh[4 * HH];   // 12 KB combine buffer

    const int u = blockIdx.x, b = blockIdx.y;
    const int tid = threadIdx.x;
    const int grp = (tid >= 192) ? 1 : 0;
    const int lt  = tid - grp * 192;          // lt*4 = h base (192*4 = 768)

    for (int i = tid; i < SS; i += 384) tn[i] = turn[b * SS + i];
    __syncthreads();

    // run bounds: [beg, end) with tn == u  (tn sorted ascending)
    int L = 0, R = SS;
    while (L < R) { int m = (L + R) >> 1; if (tn[m] < u) L = m + 1; else R = m; }
    const int beg = L;
    L = beg; R = SS;
    while (L < R) { int m = (L + R) >> 1; if (tn[m] <= u) L = m + 1; else R = m; }
    const int end = L;

    for (int i = beg + tid; i < end; i += 384) {
        float a = am[b * SS + i]; c2s[i] = a * a;
        idvs[i] = qa[b * SS + i];
    }
    __syncthreads();

    float4 acc[4];
#pragma unroll
    for (int i = 0; i < 4; ++i) acc[i] = make_float4(0.f, 0.f, 0.f, 0.f);

    const float* xb = x + (size_t)b * SS * HH + lt * 4;
    for (int s0 = beg; s0 < end; s0 += 16) {
        float4 v[8];
#pragma unroll
        for (int k = 0; k < 8; ++k) {
            const int ss = s0 + 2 * k + grp;
            v[k] = (ss < end) ? *(const float4*)(xb + (size_t)ss * HH)
                              : make_float4(0.f, 0.f, 0.f, 0.f);
        }
#pragma unroll
        for (int k = 0; k < 8; ++k) {
            const int ss = s0 + 2 * k + grp;
            if (ss < end) {                       // wave-uniform (group-wide)
                const float cc = c2s[ss];
                const int id = idvs[ss];
                const float4 xv = v[k];
                if (id == 0) { acc[0].x += xv.x * cc; acc[0].y += xv.y * cc;
                               acc[0].z += xv.z * cc; acc[0].w += xv.w * cc; }
                else if (id == 1) { acc[1].x += xv.x * cc; acc[1].y += xv.y * cc;
                                    acc[1].z += xv.z * cc; acc[1].w += xv.w * cc; }
                else if (id == 2) { acc[2].x += xv.x * cc; acc[2].y += xv.y * cc;
                                    acc[2].z += xv.z * cc; acc[2].w += xv.w * cc; }
                else { acc[3].x += xv.x * cc; acc[3].y += xv.y * cc;
                       acc[3].z += xv.z * cc; acc[3].w += xv.w * cc; }
            }
        }
    }

    if (grp == 1) {
#pragma unroll
        for (int i = 0; i < 4; ++i)
            *(float4*)&Gh[i * HH + lt * 4] = acc[i];
    }
    __syncthreads();
    if (grp == 0) {
        float* go = g_G + ((size_t)(b * NT + u) * 4) * HH + lt * 4;
#pragma unroll
        for (int i = 0; i < 4; ++i) {
            const float4 o = *(const float4*)&Gh[i * HH + lt * 4];
            float4 s;
            s.x = acc[i].x + o.x; s.y = acc[i].y + o.y;
            s.z = acc[i].z + o.z; s.w = acc[i].w + o.w;
            *(float4*)(go + (size_t)i * HH) = s;
        }
    }
}

// ---------------------------------------------------------------------------
// k_w: W[b][v] = sum_{u in [v-2,v+2]} G[b][u]; also emits snum (column sums
// of G: sq = T1+T2, sa = T0+T2, sn = T3). grid (4, BB): block owns a
// 192-float h-quarter; stages G[b][*][*][quarter] (48 KB) in LDS once.
// ---------------------------------------------------------------------------
__global__ __launch_bounds__(256) void k_w() {
    __shared__ float Gl[NT * 4 * 192];   // 48 KB
    const int qh = blockIdx.x, b = blockIdx.y, tid = threadIdx.x;

    for (int idx = tid * 4; idx < NT * 4 * 192; idx += 1024) {
        const int u = idx / 768, rem = idx % 768;
        const int i = rem / 192, hh = rem % 192;
        *(float4*)&Gl[idx] =
            *(const float4*)(g_G + ((size_t)(b * NT + u) * 4 + i) * HH + qh * 192 + hh);
    }
    __syncthreads();

    for (int idx = tid * 4; idx < NT * 4 * 192; idx += 1024) {
        const int v = idx / 768, rem = idx % 768;
        const int i = rem / 192, hh = rem % 192;
        const int ulo = (v - VR < 0) ? 0 : v - VR;
        const int uhi = (v + VR > NT - 1) ? NT - 1 : v + VR;
        float4 s = make_float4(0.f, 0.f, 0.f, 0.f);
        for (int u = ulo; u <= uhi; ++u) {
            const float4 gv = *(const float4*)&Gl[(u * 4 + i) * 192 + hh];
            s.x += gv.x; s.y += gv.y; s.z += gv.z; s.w += gv.w;
        }
        *(float4*)(g_Wm + ((size_t)(b * NT + v) * 4 + i) * HH + qh * 192 + hh) = s;
    }

    // snum for this h-quarter (threads 0..47 own a float4 each)
    if (tid < 48) {
        const int hh = tid * 4;
        float4 t0 = make_float4(0.f,0.f,0.f,0.f), t1 = t0, t2 = t0, t3 = t0;
        for (int u = 0; u < NT; ++u) {
            const float4 g0 = *(const float4*)&Gl[(u * 4 + 0) * 192 + hh];
            const float4 g1 = *(const float4*)&Gl[(u * 4 + 1) * 192 + hh];
            const float4 g2 = *(const float4*)&Gl[(u * 4 + 2) * 192 + hh];
            const float4 g3 = *(const float4*)&Gl[(u * 4 + 3) * 192 + hh];
            t0.x += g0.x; t0.y += g0.y; t0.z += g0.z; t0.w += g0.w;
            t1.x += g1.x; t1.y += g1.y; t1.z += g1.z; t1.w += g1.w;
            t2.x += g2.x; t2.y += g2.y; t2.z += g2.z; t2.w += g2.w;
            t3.x += g3.x; t3.y += g3.y; t3.z += g3.z; t3.w += g3.w;
        }
        float4 oq, oa, on;
        oq.x = t1.x + t2.x; oq.y = t1.y + t2.y; oq.z = t1.z + t2.z; oq.w = t1.w + t2.w;
        oa.x = t0.x + t2.x; oa.y = t0.y + t2.y; oa.z = t0.z + t2.z; oa.w = t0.w + t2.w;
        on = t3;
        *(float4*)(g_snum + (size_t)(b * 3 + 0) * HH + qh * 192 + hh) = oq;
        *(float4*)(g_snum + (size_t)(b * 3 + 1) * HH + qh * 192 + hh) = oa;
        *(float4*)(g_snum + (size_t)(b * 3 + 2) * HH + qh * 192 + hh) = on;
    }
}

// ---------------------------------------------------------------------------
// k_ct: round-4 shape. Per t: d_i = x_t . W_i^(turn_t), W direct from g_Wm
// (12 float4 per v-change; first v prefetched beside the 24 x loads). All 8
// t-rows prefetched to registers. Epilogue algebra -> cw_{q,a,n}(t); cross
// numerators in registers; 37 KB LDS tree reduce -> one partial per block.
// grid (SS/32=16, BB), block 256 = 4 waves; wave owns 8 t's; lane owns
// h = ch*256 + lane*4 + {0..3}, ch = 0..2.
// ---------------------------------------------------------------------------
__global__ __launch_bounds__(256) void k_ct(const float* __restrict__ x,
                                            const float* __restrict__ am,
                                            const int* __restrict__ qa,
                                            const int* __restrict__ turn) {
    __shared__ float red[4][3 * HH];   // 36 KB
    __shared__ int   tnb[32];
    __shared__ float amb[32];
    __shared__ int   idb[32];

    const int b = blockIdx.y, ts = blockIdx.x, T0 = ts * 32;
    const int tid = threadIdx.x, w = tid >> 6, lane = tid & 63;
    if (tid < 32) {
        tnb[tid] = turn[b * SS + T0 + tid];
        amb[tid] = am[b * SS + T0 + tid];
        idb[tid] = qa[b * SS + T0 + tid];
    }
    __syncthreads();

    const float* xb = x + (size_t)b * SS * HH;
    float4 xt[8][3];
#pragma unroll
    for (int it = 0; it < 8; ++it) {
        const float* xr = xb + (size_t)(T0 + w * 8 + it) * HH + lane * 4;
        xt[it][0] = *(const float4*)(xr + 0);
        xt[it][1] = *(const float4*)(xr + 256);
        xt[it][2] = *(const float4*)(xr + 512);
    }

    // first-W prefetch: issued while the 24 x loads are still in flight
    float4 Wr[4][3];
    int curv = tnb[w * 8];
    {
        const float* Wg = g_Wm + ((size_t)(b * NT + curv) * 4) * HH + lane * 4;
#pragma unroll
        for (int i = 0; i < 4; ++i) {
            Wr[i][0] = *(const float4*)(Wg + (size_t)i * HH + 0);
            Wr[i][1] = *(const float4*)(Wg + (size_t)i * HH + 256);
            Wr[i][2] = *(const float4*)(Wg + (size_t)i * HH + 512);
        }
    }

    float xn[3][12];
#pragma unroll
    for (int c = 0; c < 3; ++c)
#pragma unroll
        for (int k = 0; k < 12; ++k) xn[c][k] = 0.0f;

#pragma unroll
    for (int it = 0; it < 8; ++it) {
        const int tl = w * 8 + it;
        const int v = tnb[tl];                 // wave-uniform
        if (v != curv) {
            curv = v;
            const float* Wg = g_Wm + ((size_t)(b * NT + v) * 4) * HH + lane * 4;
#pragma unroll
            for (int i = 0; i < 4; ++i) {
                Wr[i][0] = *(const float4*)(Wg + (size_t)i * HH + 0);
                Wr[i][1] = *(const float4*)(Wg + (size_t)i * HH + 256);
                Wr[i][2] = *(const float4*)(Wg + (size_t)i * HH + 512);
            }
        }
        float d[4];
#pragma unroll
        for (int i = 0; i < 4; ++i) {
            float s = 0;
#pragma unroll
            for (int ch = 0; ch < 3; ++ch) {
                s += xt[it][ch].x * Wr[i][ch].x + xt[it][ch].y * Wr[i][ch].y
                   + xt[it][ch].z * Wr[i][ch].z + xt[it][ch].w * Wr[i][ch].w;
            }
            d[i] = s;
        }
#pragma unroll
        for (int off = 32; off; off >>= 1) {
#pragma unroll
            for (int i = 0; i < 4; ++i) d[i] += __shfl_xor(d[i], off);
        }
        float qt, at, nt; class_masks(amb[tl], idb[tl], qt, at, nt);
        const float ant = at + nt, qnt = qt + nt, qat = qt + at;
        const float Sqq = d[1] + d[2], Sqa = d[2], Saa = d[0] + d[2], Snn = d[3];
        const float cwq = qt * (ant * Sqa + qnt * Saa + qat * Snn);
        const float cwa = at * (ant * Sqq + qnt * Sqa + qat * Snn);
        const float cwn = nt * (ant * (Sqq + Sqa) + qnt * (Sqa + Saa));
#pragma unroll
        for (int ch = 0; ch < 3; ++ch) {
            const float4 xv = xt[it][ch];
            xn[0][ch * 4 + 0] += cwq * xv.x; xn[0][ch * 4 + 1] += cwq * xv.y;
            xn[0][ch * 4 + 2] += cwq * xv.z; xn[0][ch * 4 + 3] += cwq * xv.w;
            xn[1][ch * 4 + 0] += cwa * xv.x; xn[1][ch * 4 + 1] += cwa * xv.y;
            xn[1][ch * 4 + 2] += cwa * xv.z; xn[1][ch * 4 + 3] += cwa * xv.w;
            xn[2][ch * 4 + 0] += cwn * xv.x; xn[2][ch * 4 + 1] += cwn * xv.y;
            xn[2][ch * 4 + 2] += cwn * xv.z; xn[2][ch * 4 + 3] += cwn * xv.w;
        }
    }

    // per-wave partials -> LDS, block tree reduce -> one partial per block
#pragma unroll
    for (int c = 0; c < 3; ++c) {
#pragma unroll
        for (int ch = 0; ch < 3; ++ch) {
            float4 o;
            o.x = xn[c][ch * 4 + 0]; o.y = xn[c][ch * 4 + 1];
            o.z = xn[c][ch * 4 + 2]; o.w = xn[c][ch * 4 + 3];
            *(float4*)&red[w][c * HH + ch * 256 + lane * 4] = o;
        }
    }
    __syncthreads();
    float* xo = g_xpart + (size_t)(b * NPART + ts) * 3 * HH;
    for (int idx = tid * 4; idx < 3 * HH; idx += 1024) {
        float4 r0 = *(float4*)&red[0][idx];
        float4 r1 = *(float4*)&red[1][idx];
        float4 r2 = *(float4*)&red[2][idx];
        float4 r3 = *(float4*)&red[3][idx];
        float4 o;
        o.x = r0.x + r1.x + r2.x + r3.x;
        o.y = r0.y + r1.y + r2.y + r3.y;
        o.z = r0.z + r1.z + r2.z + r3.z;
        o.w = r0.w + r1.w + r2.w + r3.w;
        *(float4*)(xo + idx) = o;
    }
}

// ---------------------------------------------------------------------------
// k_cos: dens + cosine logits per class c; snum read directly (from k_w);
// fp32 self-avg outputs for group sample 0 at out[1 + (c*GG + g)*HH + h].
// grid (3, BB), block 256.
// ---------------------------------------------------------------------------
__global__ void k_cos(const float* __restrict__ am, const int* __restrict__ qa,
                      float* __restrict__ out) {
    const int c = blockIdx.x, b = blockIdx.y, tid = threadIdx.x;
    const int wave = tid >> 6, lane = tid & 63;
    __shared__ float redd[4][3];
    __shared__ float sD[3];

    float q = 0, a = 0, n = 0;
    for (int s = tid; s < SS; s += 256) {
        float m = am[b * SS + s]; int id = qa[b * SS + s];
        float qv, av, nv; class_masks(m, id, qv, av, nv);
        q += qv; a += av; n += nv;
    }
#pragma unroll
    for (int off = 32; off; off >>= 1) {
        q += __shfl_down(q, off); a += __shfl_down(a, off); n += __shfl_down(n, off);
    }
    if (lane == 0) { redd[wave][0] = q; redd[wave][1] = a; redd[wave][2] = n; }
    __syncthreads();
    if (tid == 0) {
        float Q = 0, A = 0, N = 0;
#pragma unroll
        for (int w = 0; w < 4; ++w) { Q += redd[w][0]; A += redd[w][1]; N += redd[w][2]; }
        sD[0] = Q; sD[1] = A; sD[2] = N;
    }
    __syncthreads();
    const float Dq = sD[0], Da = sD[1], Dn = sD[2];
    const float Dself = (c == 0) ? Dq : ((c == 1) ? Da : Dn);
    const float Dcross = (c == 0) ? (Da + Dn) : ((c == 1) ? (Dq + Dn) : (Dq + Da));
    const float invS = 1.0f / (Dself + 1e-6f), invC = 1.0f / (Dcross + 1e-6f);

    float dot = 0, n1 = 0, n2 = 0;
#pragma unroll
    for (int j = 0; j < 3; ++j) {
        const int h = tid + j * 256;
        float sv = g_snum[(size_t)(b * 3 + c) * HH + h];
        float cv = 0;
        const float* xp = g_xpart + ((size_t)b * NPART * 3 + c) * HH + h;
#pragma unroll
        for (int p = 0; p < NPART; ++p) cv += xp[(size_t)p * 3 * HH];
        sv *= invS; cv *= invC;
        dot += sv * cv; n1 += sv * sv; n2 += cv * cv;
        if (b % SN == 0)
            out[1 + ((size_t)c * GG + b / SN) * HH + h] = sv;
    }
#pragma unroll
    for (int off = 32; off; off >>= 1) {
        dot += __shfl_down(dot, off); n1 += __shfl_down(n1, off); n2 += __shfl_down(n2, off);
    }
    __shared__ float red2[4][3];
    if (lane == 0) { red2[wave][0] = dot; red2[wave][1] = n1; red2[wave][2] = n2; }
    __syncthreads();
    if (tid == 0) {
        float D = 0, N1 = 0, N2 = 0;
#pragma unroll
        for (int w = 0; w < 4; ++w) { D += red2[w][0]; N1 += red2[w][1]; N2 += red2[w][2]; }
        float nx = fmaxf(sqrtf(N1), 1e-8f);
        float ny = fmaxf(sqrtf(N2), 1e-8f);
        float cc = D / (nx * ny);
        if (cc == 1.0f) cc = __uint_as_float(0x7FC00000u);
        g_logits[c * BB + b] = cc / 0.07f;
    }
}

// log_softmax + nanmean loss across 3 classes -> out[0] (fp32). (unchanged)
__global__ void k_loss(const float* __restrict__ labels, float* __restrict__ out) {
    __shared__ float rs[24];
    __shared__ int rc[24];
    const int tid = threadIdx.x;
    if (tid < 24) {
        int c = tid / GG, g = tid % GG;
        float lg[SN]; bool anynan = false;
        for (int j = 0; j < SN; ++j) {
            float v = g_logits[c * BB + g * SN + j];
            lg[j] = v;
            anynan = anynan || isnan(v);
        }
        float ssum = 0; int cnt = 0;
        if (!anynan) {
            float m = -1e30f;
            for (int j = 0; j < SN; ++j) m = fmaxf(m, lg[j]);
            float se = 0;
            for (int j = 0; j < SN; ++j) se += expf(lg[j] - m);
            float lse = m + logf(se);
            for (int j = 0; j < SN; ++j) ssum += (lg[j] - lse) * labels[g * SN + j];
            cnt = SN;
        }
        rs[tid] = ssum; rc[tid] = cnt;
    }
    __syncthreads();
    if (tid == 0) {
        float total = 0;
        for (int c = 0; c < 3; ++c) {
            float s = 0; int n = 0;
            for (int g = 0; g < GG; ++g) { s += rs[c * GG + g]; n += rc[c * GG + g]; }
            total += -(s / (float)n);
        }
        out[0] = total / 3.0f;
    }
}

extern "C" void kernel_launch(void* const* d_in, const int* in_sizes, int n_in,
                              void* d_out, int out_size, void* d_ws, size_t ws_size,
                              hipStream_t stream) {
    const float* x      = (const float*)d_in[0];
    const float* am     = (const float*)d_in[1];
    const float* labels = (const float*)d_in[2];
    const int*   qa     = (const int*)d_in[3];
    const int*   turn   = (const int*)d_in[4];
    float* out = (float*)d_out;

    k_g   <<<dim3(NT, BB),      384, 0, stream>>>(x, am, qa, turn);
    k_w   <<<dim3(4, BB),       256, 0, stream>>>();
    k_ct  <<<dim3(SS / 32, BB), 256, 0, stream>>>(x, am, qa, turn);
    k_cos <<<dim3(3, BB),       256, 0, stream>>>(am, qa, out);
    k_loss<<<dim3(1),           64,  0, stream>>>(labels, out);
}

// Round 11
// 232.589 us; speedup vs baseline: 1.4143x; 1.0445x over previous
//
#include <hip/hip_runtime.h>
#include <math.h>

// Problem constants (fixed by setup_inputs)
#define BB 72      // G * SAMPLE_NUMS = 8*9
#define SS 512
#define HH 768
#define GG 8
#define SN 9
#define VR 2       // VIEW_RANGE
#define NT 16      // distinct turn values (randint(0,16))
#define NPART NT   // cross-num partials per batch (one per k_ct block = per v)

// Output is FP32, layout = return order [loss | q | a | n] (verified).
// Inputs fp32, dict order.
//
// Bucket factorization (verified round 2): band(t) depends only on v=turn_t:
//   G_i^(u)[h] = sum_{turn_s=u, id_s=i} am_s^2 x_s[h]      (k_g, one x pass)
//   W_i^(v)    = sum_{u in [v-2,v+2]} G_i^(u)              (k_w, G read once)
//   d_i(t)     = x_t . W_i^(turn_t)                        (k_ct, one x pass)
// Round 20/21: k_ct decomposed by turn-run (one block per (v,b), mirroring
// k_g). W[b][v] is loaded ONCE per block (14 MB total vs ~110 MB of per-wave
// re-loads in the t-chunk decomposition); the block's x rows are the
// contiguous run; no mid-loop W reloads. Wave math unchanged (ch-mapped
// float4 lanes, 6-step shuffle reduce, LDS tree reduce -> one partial,
// indexed by v so k_cos is untouched). (Round-10 bench was an infra failure
// -- "container failed twice", no kernel signal -- resubmitting unchanged.)

__device__ float g_G [(size_t)BB * NT * 4 * HH];       // 14.2 MB
__device__ float g_Wm[(size_t)BB * NT * 4 * HH];       // 14.2 MB (windowed)
__device__ float g_snum[BB * 3 * HH];                  // self numerators
__device__ float g_xpart[(size_t)BB * NPART * 3 * HH]; // cross-num block partials
__device__ float g_logits[3 * BB];

__device__ __forceinline__ void class_masks(float am, int id, float& qv, float& av, float& nv) {
    qv = (id == 1 || id == 2) ? am : 0.0f;
    av = (id == 0 || id == 2) ? am : 0.0f;
    nv = (id == 3) ? am : 0.0f;
}

// ---------------------------------------------------------------------------
// k_g: grid (NT, BB), block 384 = 6 waves in two 192-thread groups.
// Block (u,b): binary-search run [beg,end) over LDS tn; group g sums rows
// beg+g, beg+g+2, ... (wave-uniform) id-split into 4 float4 register
// accumulators; groups combined through a 12 KB LDS stage; G[b][u] written
// once (empty run -> zeros). 8-deep guarded row batches per group.
// ---------------------------------------------------------------------------
__global__ __launch_bounds__(384) void k_g(const float* __restrict__ x,
                                           const float* __restrict__ am,
                                           const int* __restrict__ qa,
                                           const int* __restrict__ turn) {
    __shared__ int   tn[SS];
    __shared__ float c2s[SS];
    __shared__ int   idvs[SS];
    __shared__ float Gh[4 * HH];   // 12 KB combine buffer

    const int u = blockIdx.x, b = blockIdx.y;
    const int tid = threadIdx.x;
    const int grp = (tid >= 192) ? 1 : 0;
    const int lt  = tid - grp * 192;          // lt*4 = h base (192*4 = 768)

    for (int i = tid; i < SS; i += 384) tn[i] = turn[b * SS + i];
    __syncthreads();

    // run bounds: [beg, end) with tn == u  (tn sorted ascending)
    int L = 0, R = SS;
    while (L < R) { int m = (L + R) >> 1; if (tn[m] < u) L = m + 1; else R = m; }
    const int beg = L;
    L = beg; R = SS;
    while (L < R) { int m = (L + R) >> 1; if (tn[m] <= u) L = m + 1; else R = m; }
    const int end = L;

    for (int i = beg + tid; i < end; i += 384) {
        float a = am[b * SS + i]; c2s[i] = a * a;
        idvs[i] = qa[b * SS + i];
    }
    __syncthreads();

    float4 acc[4];
#pragma unroll
    for (int i = 0; i < 4; ++i) acc[i] = make_float4(0.f, 0.f, 0.f, 0.f);

    const float* xb = x + (size_t)b * SS * HH + lt * 4;
    for (int s0 = beg; s0 < end; s0 += 16) {
        float4 v[8];
#pragma unroll
        for (int k = 0; k < 8; ++k) {
            const int ss = s0 + 2 * k + grp;
            v[k] = (ss < end) ? *(const float4*)(xb + (size_t)ss * HH)
                              : make_float4(0.f, 0.f, 0.f, 0.f);
        }
#pragma unroll
        for (int k = 0; k < 8; ++k) {
            const int ss = s0 + 2 * k + grp;
            if (ss < end) {                       // wave-uniform (group-wide)
                const float cc = c2s[ss];
                const int id = idvs[ss];
                const float4 xv = v[k];
                if (id == 0) { acc[0].x += xv.x * cc; acc[0].y += xv.y * cc;
                               acc[0].z += xv.z * cc; acc[0].w += xv.w * cc; }
                else if (id == 1) { acc[1].x += xv.x * cc; acc[1].y += xv.y * cc;
                                    acc[1].z += xv.z * cc; acc[1].w += xv.w * cc; }
                else if (id == 2) { acc[2].x += xv.x * cc; acc[2].y += xv.y * cc;
                                    acc[2].z += xv.z * cc; acc[2].w += xv.w * cc; }
                else { acc[3].x += xv.x * cc; acc[3].y += xv.y * cc;
                       acc[3].z += xv.z * cc; acc[3].w += xv.w * cc; }
            }
        }
    }

    if (grp == 1) {
#pragma unroll
        for (int i = 0; i < 4; ++i)
            *(float4*)&Gh[i * HH + lt * 4] = acc[i];
    }
    __syncthreads();
    if (grp == 0) {
        float* go = g_G + ((size_t)(b * NT + u) * 4) * HH + lt * 4;
#pragma unroll
        for (int i = 0; i < 4; ++i) {
            const float4 o = *(const float4*)&Gh[i * HH + lt * 4];
            float4 s;
            s.x = acc[i].x + o.x; s.y = acc[i].y + o.y;
            s.z = acc[i].z + o.z; s.w = acc[i].w + o.w;
            *(float4*)(go + (size_t)i * HH) = s;
        }
    }
}

// ---------------------------------------------------------------------------
// k_w: W[b][v] = sum_{u in [v-2,v+2]} G[b][u]; also emits snum (column sums
// of G: sq = T1+T2, sa = T0+T2, sn = T3). grid (4, BB): block owns a
// 192-float h-quarter; stages G[b][*][*][quarter] (48 KB) in LDS once.
// ---------------------------------------------------------------------------
__global__ __launch_bounds__(256) void k_w() {
    __shared__ float Gl[NT * 4 * 192];   // 48 KB
    const int qh = blockIdx.x, b = blockIdx.y, tid = threadIdx.x;

    for (int idx = tid * 4; idx < NT * 4 * 192; idx += 1024) {
        const int u = idx / 768, rem = idx % 768;
        const int i = rem / 192, hh = rem % 192;
        *(float4*)&Gl[idx] =
            *(const float4*)(g_G + ((size_t)(b * NT + u) * 4 + i) * HH + qh * 192 + hh);
    }
    __syncthreads();

    for (int idx = tid * 4; idx < NT * 4 * 192; idx += 1024) {
        const int v = idx / 768, rem = idx % 768;
        const int i = rem / 192, hh = rem % 192;
        const int ulo = (v - VR < 0) ? 0 : v - VR;
        const int uhi = (v + VR > NT - 1) ? NT - 1 : v + VR;
        float4 s = make_float4(0.f, 0.f, 0.f, 0.f);
        for (int u = ulo; u <= uhi; ++u) {
            const float4 gv = *(const float4*)&Gl[(u * 4 + i) * 192 + hh];
            s.x += gv.x; s.y += gv.y; s.z += gv.z; s.w += gv.w;
        }
        *(float4*)(g_Wm + ((size_t)(b * NT + v) * 4 + i) * HH + qh * 192 + hh) = s;
    }

    // snum for this h-quarter (threads 0..47 own a float4 each)
    if (tid < 48) {
        const int hh = tid * 4;
        float4 t0 = make_float4(0.f,0.f,0.f,0.f), t1 = t0, t2 = t0, t3 = t0;
        for (int u = 0; u < NT; ++u) {
            const float4 g0 = *(const float4*)&Gl[(u * 4 + 0) * 192 + hh];
            const float4 g1 = *(const float4*)&Gl[(u * 4 + 1) * 192 + hh];
            const float4 g2 = *(const float4*)&Gl[(u * 4 + 2) * 192 + hh];
            const float4 g3 = *(const float4*)&Gl[(u * 4 + 3) * 192 + hh];
            t0.x += g0.x; t0.y += g0.y; t0.z += g0.z; t0.w += g0.w;
            t1.x += g1.x; t1.y += g1.y; t1.z += g1.z; t1.w += g1.w;
            t2.x += g2.x; t2.y += g2.y; t2.z += g2.z; t2.w += g2.w;
            t3.x += g3.x; t3.y += g3.y; t3.z += g3.z; t3.w += g3.w;
        }
        float4 oq, oa, on;
        oq.x = t1.x + t2.x; oq.y = t1.y + t2.y; oq.z = t1.z + t2.z; oq.w = t1.w + t2.w;
        oa.x = t0.x + t2.x; oa.y = t0.y + t2.y; oa.z = t0.z + t2.z; oa.w = t0.w + t2.w;
        on = t3;
        *(float4*)(g_snum + (size_t)(b * 3 + 0) * HH + qh * 192 + hh) = oq;
        *(float4*)(g_snum + (size_t)(b * 3 + 1) * HH + qh * 192 + hh) = oa;
        *(float4*)(g_snum + (size_t)(b * 3 + 2) * HH + qh * 192 + hh) = on;
    }
}

// ---------------------------------------------------------------------------
// k_ct: grid (NT, BB), block 256 = 4 waves. Block (v,b): run [beg,end) via
// binary search over LDS tn; W[b][v] loaded ONCE into registers; wave handles
// rows beg+w, beg+w+4, ... with a 2-deep rolling x prefetch. Per t: 4 dots,
// 6-step shuffle reduce, epilogue algebra -> cw_{q,a,n}; cross numerators in
// registers; LDS tree reduce -> one partial per block at g_xpart[b][v].
// lane owns h = ch*256 + lane*4 + {0..3}, ch = 0..2.
// ---------------------------------------------------------------------------
__global__ __launch_bounds__(256) void k_ct(const float* __restrict__ x,
                                            const float* __restrict__ am,
                                            const int* __restrict__ qa,
                                            const int* __restrict__ turn) {
    __shared__ float red[4][3 * HH];   // 36 KB
    __shared__ int   tns[SS];
    __shared__ float ams[SS];
    __shared__ int   ids[SS];

    const int v = blockIdx.x, b = blockIdx.y;
    const int tid = threadIdx.x, w = tid >> 6, lane = tid & 63;
    for (int i = tid; i < SS; i += 256) {
        tns[i] = turn[b * SS + i];
        ams[i] = am[b * SS + i];
        ids[i] = qa[b * SS + i];
    }
    __syncthreads();

    // run bounds: [beg, end) with tns == v
    int L = 0, R = SS;
    while (L < R) { int m = (L + R) >> 1; if (tns[m] < v) L = m + 1; else R = m; }
    const int beg = L;
    L = beg; R = SS;
    while (L < R) { int m = (L + R) >> 1; if (tns[m] <= v) L = m + 1; else R = m; }
    const int end = L;

    float xn[3][12];
#pragma unroll
    for (int c = 0; c < 3; ++c)
#pragma unroll
        for (int k = 0; k < 12; ++k) xn[c][k] = 0.0f;

    if (beg < end) {
        // W[b][v] once per block
        float4 Wr[4][3];
        {
            const float* Wg = g_Wm + ((size_t)(b * NT + v) * 4) * HH + lane * 4;
#pragma unroll
            for (int i = 0; i < 4; ++i) {
                Wr[i][0] = *(const float4*)(Wg + (size_t)i * HH + 0);
                Wr[i][1] = *(const float4*)(Wg + (size_t)i * HH + 256);
                Wr[i][2] = *(const float4*)(Wg + (size_t)i * HH + 512);
            }
        }
        const float* xb = x + (size_t)b * SS * HH + lane * 4;

        int s = beg + w;
        float4 xA[3];
        if (s < end) {
            const float* xr = xb + (size_t)s * HH;
            xA[0] = *(const float4*)(xr + 0);
            xA[1] = *(const float4*)(xr + 256);
            xA[2] = *(const float4*)(xr + 512);
        }
        for (; s < end; s += 4) {
            float4 xB[3];
            const int sn = s + 4;
            if (sn < end) {                       // wave-uniform
                const float* xr = xb + (size_t)sn * HH;
                xB[0] = *(const float4*)(xr + 0);
                xB[1] = *(const float4*)(xr + 256);
                xB[2] = *(const float4*)(xr + 512);
            }
            float d[4];
#pragma unroll
            for (int i = 0; i < 4; ++i) {
                float sacc = 0;
#pragma unroll
                for (int ch = 0; ch < 3; ++ch) {
                    sacc += xA[ch].x * Wr[i][ch].x + xA[ch].y * Wr[i][ch].y
                          + xA[ch].z * Wr[i][ch].z + xA[ch].w * Wr[i][ch].w;
                }
                d[i] = sacc;
            }
#pragma unroll
            for (int off = 32; off; off >>= 1) {
#pragma unroll
                for (int i = 0; i < 4; ++i) d[i] += __shfl_xor(d[i], off);
            }
            float qt, at, nt; class_masks(ams[s], ids[s], qt, at, nt);
            const float ant = at + nt, qnt = qt + nt, qat = qt + at;
            const float Sqq = d[1] + d[2], Sqa = d[2], Saa = d[0] + d[2], Snn = d[3];
            const float cwq = qt * (ant * Sqa + qnt * Saa + qat * Snn);
            const float cwa = at * (ant * Sqq + qnt * Sqa + qat * Snn);
            const float cwn = nt * (ant * (Sqq + Sqa) + qnt * (Sqa + Saa));
#pragma unroll
            for (int ch = 0; ch < 3; ++ch) {
                const float4 xv = xA[ch];
                xn[0][ch * 4 + 0] += cwq * xv.x; xn[0][ch * 4 + 1] += cwq * xv.y;
                xn[0][ch * 4 + 2] += cwq * xv.z; xn[0][ch * 4 + 3] += cwq * xv.w;
                xn[1][ch * 4 + 0] += cwa * xv.x; xn[1][ch * 4 + 1] += cwa * xv.y;
                xn[1][ch * 4 + 2] += cwa * xv.z; xn[1][ch * 4 + 3] += cwa * xv.w;
                xn[2][ch * 4 + 0] += cwn * xv.x; xn[2][ch * 4 + 1] += cwn * xv.y;
                xn[2][ch * 4 + 2] += cwn * xv.z; xn[2][ch * 4 + 3] += cwn * xv.w;
            }
#pragma unroll
            for (int ch = 0; ch < 3; ++ch) xA[ch] = xB[ch];
        }
    }

    // per-wave partials -> LDS, block tree reduce -> one partial per block
#pragma unroll
    for (int c = 0; c < 3; ++c) {
#pragma unroll
        for (int ch = 0; ch < 3; ++ch) {
            float4 o;
            o.x = xn[c][ch * 4 + 0]; o.y = xn[c][ch * 4 + 1];
            o.z = xn[c][ch * 4 + 2]; o.w = xn[c][ch * 4 + 3];
            *(float4*)&red[w][c * HH + ch * 256 + lane * 4] = o;
        }
    }
    __syncthreads();
    float* xo = g_xpart + (size_t)(b * NPART + v) * 3 * HH;
    for (int idx = tid * 4; idx < 3 * HH; idx += 1024) {
        float4 r0 = *(float4*)&red[0][idx];
        float4 r1 = *(float4*)&red[1][idx];
        float4 r2 = *(float4*)&red[2][idx];
        float4 r3 = *(float4*)&red[3][idx];
        float4 o;
        o.x = r0.x + r1.x + r2.x + r3.x;
        o.y = r0.y + r1.y + r2.y + r3.y;
        o.z = r0.z + r1.z + r2.z + r3.z;
        o.w = r0.w + r1.w + r2.w + r3.w;
        *(float4*)(xo + idx) = o;
    }
}

// ---------------------------------------------------------------------------
// k_cos: dens + cosine logits per class c; snum read directly (from k_w);
// fp32 self-avg outputs for group sample 0 at out[1 + (c*GG + g)*HH + h].
// grid (3, BB), block 256.
// ---------------------------------------------------------------------------
__global__ void k_cos(const float* __restrict__ am, const int* __restrict__ qa,
                      float* __restrict__ out) {
    const int c = blockIdx.x, b = blockIdx.y, tid = threadIdx.x;
    const int wave = tid >> 6, lane = tid & 63;
    __shared__ float redd[4][3];
    __shared__ float sD[3];

    float q = 0, a = 0, n = 0;
    for (int s = tid; s < SS; s += 256) {
        float m = am[b * SS + s]; int id = qa[b * SS + s];
        float qv, av, nv; class_masks(m, id, qv, av, nv);
        q += qv; a += av; n += nv;
    }
#pragma unroll
    for (int off = 32; off; off >>= 1) {
        q += __shfl_down(q, off); a += __shfl_down(a, off); n += __shfl_down(n, off);
    }
    if (lane == 0) { redd[wave][0] = q; redd[wave][1] = a; redd[wave][2] = n; }
    __syncthreads();
    if (tid == 0) {
        float Q = 0, A = 0, N = 0;
#pragma unroll
        for (int w = 0; w < 4; ++w) { Q += redd[w][0]; A += redd[w][1]; N += redd[w][2]; }
        sD[0] = Q; sD[1] = A; sD[2] = N;
    }
    __syncthreads();
    const float Dq = sD[0], Da = sD[1], Dn = sD[2];
    const float Dself = (c == 0) ? Dq : ((c == 1) ? Da : Dn);
    const float Dcross = (c == 0) ? (Da + Dn) : ((c == 1) ? (Dq + Dn) : (Dq + Da));
    const float invS = 1.0f / (Dself + 1e-6f), invC = 1.0f / (Dcross + 1e-6f);

    float dot = 0, n1 = 0, n2 = 0;
#pragma unroll
    for (int j = 0; j < 3; ++j) {
        const int h = tid + j * 256;
        float sv = g_snum[(size_t)(b * 3 + c) * HH + h];
        float cv = 0;
        const float* xp = g_xpart + ((size_t)b * NPART * 3 + c) * HH + h;
#pragma unroll
        for (int p = 0; p < NPART; ++p) cv += xp[(size_t)p * 3 * HH];
        sv *= invS; cv *= invC;
        dot += sv * cv; n1 += sv * sv; n2 += cv * cv;
        if (b % SN == 0)
            out[1 + ((size_t)c * GG + b / SN) * HH + h] = sv;
    }
#pragma unroll
    for (int off = 32; off; off >>= 1) {
        dot += __shfl_down(dot, off); n1 += __shfl_down(n1, off); n2 += __shfl_down(n2, off);
    }
    __shared__ float red2[4][3];
    if (lane == 0) { red2[wave][0] = dot; red2[wave][1] = n1; red2[wave][2] = n2; }
    __syncthreads();
    if (tid == 0) {
        float D = 0, N1 = 0, N2 = 0;
#pragma unroll
        for (int w = 0; w < 4; ++w) { D += red2[w][0]; N1 += red2[w][1]; N2 += red2[w][2]; }
        float nx = fmaxf(sqrtf(N1), 1e-8f);
        float ny = fmaxf(sqrtf(N2), 1e-8f);
        float cc = D / (nx * ny);
        if (cc == 1.0f) cc = __uint_as_float(0x7FC00000u);
        g_logits[c * BB + b] = cc / 0.07f;
    }
}

// log_softmax + nanmean loss across 3 classes -> out[0] (fp32). (unchanged)
__global__ void k_loss(const float* __restrict__ labels, float* __restrict__ out) {
    __shared__ float rs[24];
    __shared__ int rc[24];
    const int tid = threadIdx.x;
    if (tid < 24) {
        int c = tid / GG, g = tid % GG;
        float lg[SN]; bool anynan = false;
        for (int j = 0; j < SN; ++j) {
            float v = g_logits[c * BB + g * SN + j];
            lg[j] = v;
            anynan = anynan || isnan(v);
        }
        float ssum = 0; int cnt = 0;
        if (!anynan) {
            float m = -1e30f;
            for (int j = 0; j < SN; ++j) m = fmaxf(m, lg[j]);
            float se = 0;
            for (int j = 0; j < SN; ++j) se += expf(lg[j] - m);
            float lse = m + logf(se);
            for (int j = 0; j < SN; ++j) ssum += (lg[j] - lse) * labels[g * SN + j];
            cnt = SN;
        }
        rs[tid] = ssum; rc[tid] = cnt;
    }
    __syncthreads();
    if (tid == 0) {
        float total = 0;
        for (int c = 0; c < 3; ++c) {
            float s = 0; int n = 0;
            for (int g = 0; g < GG; ++g) { s += rs[c * GG + g]; n += rc[c * GG + g]; }
            total += -(s / (float)n);
        }
        out[0] = total / 3.0f;
    }
}

extern "C" void kernel_launch(void* const* d_in, const int* in_sizes, int n_in,
                              void* d_out, int out_size, void* d_ws, size_t ws_size,
                              hipStream_t stream) {
    const float* x      = (const float*)d_in[0];
    const float* am     = (const float*)d_in[1];
    const float* labels = (const float*)d_in[2];
    const int*   qa     = (const int*)d_in[3];
    const int*   turn   = (const int*)d_in[4];
    float* out = (float*)d_out;

    k_g   <<<dim3(NT, BB), 384, 0, stream>>>(x, am, qa, turn);
    k_w   <<<dim3(4, BB),  256, 0, stream>>>();
    k_ct  <<<dim3(NT, BB), 256, 0, stream>>>(x, am, qa, turn);
    k_cos <<<dim3(3, BB),  256, 0, stream>>>(am, qa, out);
    k_loss<<<dim3(1),      64,  0, stream>>>(labels, out);
}